// Round 1
// baseline (954.252 us; speedup 1.0000x reference)
//
#include <hip/hip_runtime.h>

#define BDIM 4
#define CDIM 128
#define NDIM 4096
#define KSEL 10

// ---------------------------------------------------------------------------
// Kernel A: xx[b][n] = sum_c x[b][c][n]^2
// 256 blocks x 256 threads; 4 threads per (b,n), 32 c's each, shuffle-reduce.
// ---------------------------------------------------------------------------
__global__ __launch_bounds__(256) void xx_kernel(const float* __restrict__ x,
                                                 float* __restrict__ xx) {
  int t = threadIdx.x;
  int nl = t >> 2;
  int part = t & 3;
  int g = blockIdx.x * 64 + nl;      // 0..B*N-1
  int b = g >> 12;
  int n = g & (NDIM - 1);
  const float* xp = x + (size_t)b * CDIM * NDIM + n;
  float s = 0.f;
  int c0 = part * 32;
#pragma unroll
  for (int i = 0; i < 32; ++i) {
    float v = xp[(size_t)(c0 + i) * NDIM];
    s += v * v;
  }
  s += __shfl_xor(s, 1, 4);
  s += __shfl_xor(s, 2, 4);
  if (part == 0) xx[g] = s;
}

// ---------------------------------------------------------------------------
// Kernel B: fused pairwise-distance GEMM + streaming top-10 per row.
// Block: (b, 64-row group). 256 threads.
// GEMM phase: 64x128 pd tile per m-step, c chunked by 32 through LDS,
//             thread tile 4 rows x 8 cols (32 FMA : 3 ds_read_b128 per c).
// Top-k phase: scores staged to LDS; 4 threads/row each keep a private
//             top-10 (static register arrays), merged at the end with
//             (value desc, index asc) tie-break.
// ---------------------------------------------------------------------------
__global__ __launch_bounds__(256) void topk_kernel(const float* __restrict__ x,
                                                   const float* __restrict__ xxg,
                                                   int* __restrict__ idxout) {
  const int N = NDIM;
  int bb = blockIdx.y;
  int n0 = blockIdx.x * 64;
  int t = threadIdx.x;
  int tx = t & 15, ty = t >> 4;
  int tx8 = tx * 8, ty4 = ty * 4;

  __shared__ float xn_s[32 * 64];    //  8 KB  [cc][r]
  __shared__ float xm_s[32 * 128];   // 16 KB  [cc][m]
  __shared__ float xx_s[128];        // 0.5 KB
  __shared__ float sc_s[64 * 132];   // 33 KB  scores (+pad); reused for merge

  const float* xb = x + (size_t)bb * CDIM * N;
  const float* xxb = xxg + (size_t)bb * N;

  // private top-10: static indexing only (dynamic reg indexing -> scratch)
  float tv[KSEL];
  int ti[KSEL];
#pragma unroll
  for (int s = 0; s < KSEL; ++s) { tv[s] = -1e30f; ti[s] = 0x7fffffff; }
  float minv = -1e30f;
  int mini = 0x7fffffff;
  int minp = 0;

  // staging address precompute
  int xn_cc[2], xn_q[2], xm_cc[4], xm_q[4];
#pragma unroll
  for (int p = 0; p < 2; ++p) { int i4 = t + 256 * p; xn_cc[p] = i4 >> 4; xn_q[p] = (i4 & 15) * 4; }
#pragma unroll
  for (int p = 0; p < 4; ++p) { int i4 = t + 256 * p; xm_cc[p] = i4 >> 5; xm_q[p] = (i4 & 31) * 4; }

  float4 pxn[2], pxm[4];
  auto issue = [&](int u) {  // u = mt*4 + ch, prefetch global->regs
    int m0u = (u >> 2) * 128;
    int c0u = (u & 3) * 32;
#pragma unroll
    for (int p = 0; p < 2; ++p)
      pxn[p] = *(const float4*)&xb[(size_t)(c0u + xn_cc[p]) * N + n0 + xn_q[p]];
#pragma unroll
    for (int p = 0; p < 4; ++p)
      pxm[p] = *(const float4*)&xb[(size_t)(c0u + xm_cc[p]) * N + m0u + xm_q[p]];
  };

  issue(0);

  for (int mt = 0; mt < 32; ++mt) {
    int m0 = mt * 128;
    float acc[4][8];
#pragma unroll
    for (int i = 0; i < 4; ++i)
#pragma unroll
      for (int j = 0; j < 8; ++j) acc[i][j] = 0.f;

    for (int ch = 0; ch < 4; ++ch) {
      int u = mt * 4 + ch;
      __syncthreads();  // prior LDS consumers done
#pragma unroll
      for (int p = 0; p < 2; ++p) *(float4*)&xn_s[xn_cc[p] * 64 + xn_q[p]] = pxn[p];
#pragma unroll
      for (int p = 0; p < 4; ++p) *(float4*)&xm_s[xm_cc[p] * 128 + xm_q[p]] = pxm[p];
      if (ch == 0 && t < 128) xx_s[t] = xxb[m0 + t];
      __syncthreads();
      if (u + 1 < 128) issue(u + 1);  // overlap next stage loads with compute

#pragma unroll 8
      for (int cc = 0; cc < 32; ++cc) {
        float4 a = *(const float4*)&xn_s[cc * 64 + ty4];
        float4 b0 = *(const float4*)&xm_s[cc * 128 + tx8];
        float4 b1 = *(const float4*)&xm_s[cc * 128 + tx8 + 4];
        float av[4] = {a.x, a.y, a.z, a.w};
        float bv[8] = {b0.x, b0.y, b0.z, b0.w, b1.x, b1.y, b1.z, b1.w};
#pragma unroll
        for (int i = 0; i < 4; ++i)
#pragma unroll
          for (int j = 0; j < 8; ++j) acc[i][j] += av[i] * bv[j];
      }
    }

    // score = 2*dot - ||x_m||^2  (same ranking as pd; per-row const dropped)
    {
      float4 xq0 = *(const float4*)&xx_s[tx8];
      float4 xq1 = *(const float4*)&xx_s[tx8 + 4];
      float xv[8] = {xq0.x, xq0.y, xq0.z, xq0.w, xq1.x, xq1.y, xq1.z, xq1.w};
#pragma unroll
      for (int i = 0; i < 4; ++i) {
        int r = ty4 + i;
#pragma unroll
        for (int j = 0; j < 8; ++j)
          sc_s[r * 132 + tx8 + j] = 2.f * acc[i][j] - xv[j];
      }
    }
    __syncthreads();

    // streaming top-10 update: thread (rr,q) scans cols q*32..q*32+31 ascending
    {
      int rr = t >> 2, q = t & 3;
      const float* srow = &sc_s[rr * 132 + q * 32];
      int gbase = m0 + q * 32;
#pragma unroll 8
      for (int i = 0; i < 32; ++i) {
        float v = srow[i];
        int gm = gbase + i;
        if (v > minv || (v == minv && gm < mini)) {
#pragma unroll
          for (int s = 0; s < KSEL; ++s)
            if (minp == s) { tv[s] = v; ti[s] = gm; }
          // rescan for new min: worst = (smallest val, then largest idx)
          minv = tv[0]; mini = ti[0]; minp = 0;
#pragma unroll
          for (int s = 1; s < KSEL; ++s)
            if (tv[s] < minv || (tv[s] == minv && ti[s] > mini)) {
              minv = tv[s]; mini = ti[s]; minp = s;
            }
        }
      }
    }
    // next tile's chunk-top barrier protects sc_s / xx_s before overwrite
  }

  // ----- merge 4 partial lists per row -> final top-10 indices -----
  __syncthreads();
  {
    int rr = t >> 2, q = t & 3;
    float* mv = sc_s;                       // [64][40] values
    int* mi = (int*)(sc_s + 64 * 40);       // [64][40] indices
#pragma unroll
    for (int s = 0; s < KSEL; ++s) {
      mv[rr * 40 + q * 10 + s] = tv[s];
      mi[rr * 40 + q * 10 + s] = ti[s];
    }
  }
  __syncthreads();
  if (t < 64) {
    int row = t;
    float* mv = sc_s + row * 40;
    int* mi = (int*)(sc_s + 64 * 40) + row * 40;
    int* op = idxout + ((size_t)bb * N + n0 + row) * KSEL;
    for (int s = 0; s < KSEL; ++s) {
      float bvv = -3e38f;
      int bi = 0x7fffffff, bp = 0;
      for (int j = 0; j < 40; ++j) {
        float v = mv[j];
        int id = mi[j];
        if (v > bvv || (v == bvv && id < bi)) { bvv = v; bi = id; bp = j; }
      }
      mv[bp] = -3e38f;
      op[s] = bi;
    }
  }
}

// ---------------------------------------------------------------------------
// Kernel C: Md[b][c][n] = mean_k x[b][c][idx[b][n][k]] - x[b][c][n]
// One block per (b,c): stage the whole 16KB row in LDS -> all gathers LDS-local.
// ---------------------------------------------------------------------------
__global__ __launch_bounds__(256) void gather_kernel(const float* __restrict__ x,
                                                     const int* __restrict__ idxg,
                                                     float* __restrict__ Md) {
  const int N = NDIM;
  int bb = blockIdx.y, c = blockIdx.x;
  __shared__ float row_s[NDIM];
  const float* rowg = x + (size_t)(bb * CDIM + c) * N;
  int t = threadIdx.x;
#pragma unroll
  for (int p = 0; p < 4; ++p) {
    int i4 = t + 256 * p;
    *(float4*)&row_s[i4 * 4] = *(const float4*)&rowg[i4 * 4];
  }
  __syncthreads();
  float* outp = Md + (size_t)(bb * CDIM + c) * N;
  const int* ib = idxg + (size_t)bb * N * KSEL;
  for (int p = 0; p < 16; ++p) {
    int n = t + 256 * p;
    const int* ip = ib + (size_t)n * KSEL;
    float s = 0.f;
#pragma unroll
    for (int k = 0; k < KSEL; ++k) s += row_s[ip[k]];
    outp[n] = s * 0.1f - row_s[n];
  }
}

// ---------------------------------------------------------------------------
// Kernel D: out[b][o][n] = sum_c W[o][c]*Md[b][c][n] + W[o][128+c]*x[b][c][n] + bias[o]
// Block tile 64o x 128n, thread tile 4x8, c chunked by 32.
// ---------------------------------------------------------------------------
__global__ __launch_bounds__(256) void out_kernel(const float* __restrict__ Md,
                                                  const float* __restrict__ x,
                                                  const float* __restrict__ W,
                                                  const float* __restrict__ bias,
                                                  float* __restrict__ out) {
  const int N = NDIM, O = 256;
  int bb = blockIdx.z;
  int o0 = blockIdx.y * 64;
  int n0 = blockIdx.x * 128;
  int t = threadIdx.x;
  int tx = t & 15, ty = t >> 4;
  int tx8 = tx * 8, ty4 = ty * 4;

  __shared__ float w1_s[32 * 64];    // [cc][o]
  __shared__ float w2_s[32 * 64];
  __shared__ float md_s[32 * 128];   // [cc][n]
  __shared__ float x_s[32 * 128];

  float acc[4][8];
#pragma unroll
  for (int i = 0; i < 4; ++i)
#pragma unroll
    for (int j = 0; j < 8; ++j) acc[i][j] = 0.f;

  for (int ch = 0; ch < 4; ++ch) {
    int c0 = ch * 32;
    __syncthreads();
    // stage W chunks transposed: [cc][o]
#pragma unroll
    for (int p = 0; p < 2; ++p) {
      int i = t + 256 * p;  // 0..511
      int oo = i >> 3, q = i & 7;
      float4 v1 = *(const float4*)&W[(size_t)(o0 + oo) * 256 + c0 + q * 4];
      float4 v2 = *(const float4*)&W[(size_t)(o0 + oo) * 256 + 128 + c0 + q * 4];
      w1_s[(q * 4 + 0) * 64 + oo] = v1.x;
      w1_s[(q * 4 + 1) * 64 + oo] = v1.y;
      w1_s[(q * 4 + 2) * 64 + oo] = v1.z;
      w1_s[(q * 4 + 3) * 64 + oo] = v1.w;
      w2_s[(q * 4 + 0) * 64 + oo] = v2.x;
      w2_s[(q * 4 + 1) * 64 + oo] = v2.y;
      w2_s[(q * 4 + 2) * 64 + oo] = v2.z;
      w2_s[(q * 4 + 3) * 64 + oo] = v2.w;
    }
    // stage Md / x chunks
#pragma unroll
    for (int p = 0; p < 4; ++p) {
      int i = t + 256 * p;  // 0..1023
      int cc = i >> 5, q = (i & 31) * 4;
      *(float4*)&md_s[cc * 128 + q] =
          *(const float4*)&Md[(size_t)(bb * CDIM + c0 + cc) * N + n0 + q];
      *(float4*)&x_s[cc * 128 + q] =
          *(const float4*)&x[(size_t)(bb * CDIM + c0 + cc) * N + n0 + q];
    }
    __syncthreads();
#pragma unroll 8
    for (int cc = 0; cc < 32; ++cc) {
      float4 a1 = *(const float4*)&w1_s[cc * 64 + ty4];
      float4 a2 = *(const float4*)&w2_s[cc * 64 + ty4];
      float4 b1a = *(const float4*)&md_s[cc * 128 + tx8];
      float4 b1b = *(const float4*)&md_s[cc * 128 + tx8 + 4];
      float4 b2a = *(const float4*)&x_s[cc * 128 + tx8];
      float4 b2b = *(const float4*)&x_s[cc * 128 + tx8 + 4];
      float a1v[4] = {a1.x, a1.y, a1.z, a1.w};
      float a2v[4] = {a2.x, a2.y, a2.z, a2.w};
      float b1v[8] = {b1a.x, b1a.y, b1a.z, b1a.w, b1b.x, b1b.y, b1b.z, b1b.w};
      float b2v[8] = {b2a.x, b2a.y, b2a.z, b2a.w, b2b.x, b2b.y, b2b.z, b2b.w};
#pragma unroll
      for (int i = 0; i < 4; ++i)
#pragma unroll
        for (int j = 0; j < 8; ++j)
          acc[i][j] += a1v[i] * b1v[j] + a2v[i] * b2v[j];
    }
  }

#pragma unroll
  for (int i = 0; i < 4; ++i) {
    int o = o0 + ty4 + i;
    float bv = bias[o];
    float4 r0 = make_float4(acc[i][0] + bv, acc[i][1] + bv, acc[i][2] + bv, acc[i][3] + bv);
    float4 r1 = make_float4(acc[i][4] + bv, acc[i][5] + bv, acc[i][6] + bv, acc[i][7] + bv);
    float* po = out + (size_t)(bb * O + o) * N + n0 + tx8;
    *(float4*)&po[0] = r0;
    *(float4*)&po[4] = r1;
  }
}

// ---------------------------------------------------------------------------
extern "C" void kernel_launch(void* const* d_in, const int* in_sizes, int n_in,
                              void* d_out, int out_size, void* d_ws, size_t ws_size,
                              hipStream_t stream) {
  const float* x = (const float*)d_in[0];     // (4,128,4096) fp32
  const float* W = (const float*)d_in[1];     // (256,256,1,1) fp32
  const float* bias = (const float*)d_in[2];  // (256,) fp32
  float* out = (float*)d_out;                 // (4,256,4096) fp32

  // workspace carve (all 16B-aligned offsets)
  float* xx = (float*)d_ws;                                   // 16384 f = 64 KB
  int* idx = (int*)((char*)d_ws + 65536);                     // 163840 i = 640 KB
  float* Md = (float*)((char*)d_ws + 65536 + 655360);         // 2M f = 8 MB

  xx_kernel<<<dim3(256), 256, 0, stream>>>(x, xx);
  topk_kernel<<<dim3(64, 4), 256, 0, stream>>>(x, xx, idx);
  gather_kernel<<<dim3(128, 4), 256, 0, stream>>>(x, idx, Md);
  out_kernel<<<dim3(32, 4, 4), 256, 0, stream>>>(Md, x, W, bias, out);
}

// Round 2
// 774.406 us; speedup vs baseline: 1.2322x; 1.2322x over previous
//
#include <hip/hip_runtime.h>

#define BDIM 4
#define CDIM 128
#define NDIM 4096
#define KSEL 10
#define MSPLIT 8
#define MT_PER (NDIM / MSPLIT / 128)  // 4 m-tiles of 128 per block

// ---------------------------------------------------------------------------
// Kernel A: xx[b][n] = sum_c x[b][c][n]^2
// ---------------------------------------------------------------------------
__global__ __launch_bounds__(256) void xx_kernel(const float* __restrict__ x,
                                                 float* __restrict__ xx) {
  int t = threadIdx.x;
  int nl = t >> 2;
  int part = t & 3;
  int g = blockIdx.x * 64 + nl;      // 0..B*N-1
  int b = g >> 12;
  int n = g & (NDIM - 1);
  const float* xp = x + (size_t)b * CDIM * NDIM + n;
  float s = 0.f;
  int c0 = part * 32;
#pragma unroll
  for (int i = 0; i < 32; ++i) {
    float v = xp[(size_t)(c0 + i) * NDIM];
    s += v * v;
  }
  s += __shfl_xor(s, 1, 4);
  s += __shfl_xor(s, 2, 4);
  if (part == 0) xx[g] = s;
}

// ---------------------------------------------------------------------------
// Kernel B: fused distance-GEMM + register-resident streaming top-10,
// m-split 8 ways for occupancy. Block = (n-tile 64 rows) x (512-col split).
// Thread tile: 2 rows x 16 cols (cols = tx*4 + j*32 + e  -> conflict-free LDS).
// Emits per-(row,split) SORTED partial top-10 (val desc, idx asc).
// ---------------------------------------------------------------------------
__global__ __launch_bounds__(256, 3) void topk_kernel(const float* __restrict__ x,
                                                      const float* __restrict__ xxg,
                                                      float* __restrict__ pval,
                                                      int* __restrict__ pidx) {
  const int N = NDIM;
  int bb = blockIdx.z;
  int ms = blockIdx.y;
  int n0 = blockIdx.x * 64;
  int t = threadIdx.x;
  int tx = t & 7;          // col group 0..7
  int ty = t >> 3;         // row pair 0..31

  __shared__ float smem[6272];       // 25088 B total
  float* xn = smem;                  // [32][64]   8 KB
  float* xm = smem + 2048;           // [32][128] 16 KB
  float* xxs = smem + 6144;          // [128]     0.5 KB
  // tail-merge alias (after main loop): mv [32][80], mi [32][80]

  const float* xb = x + (size_t)bb * CDIM * N;
  const float* xxb = xxg + (size_t)bb * N;

  // two private top-10 lists (rows 2ty, 2ty+1); static indexing only
  float tv[2][KSEL];
  int ti[2][KSEL];
  float minv[2];
  int mini[2], minp[2];
#pragma unroll
  for (int i = 0; i < 2; ++i) {
#pragma unroll
    for (int s = 0; s < KSEL; ++s) { tv[i][s] = -1e30f; ti[i][s] = 0x7fffffff; }
    minv[i] = -1e30f; mini[i] = 0x7fffffff; minp[i] = 0;
  }

  // staging address precompute
  int xn_cc[2], xn_q[2], xm_cc[4], xm_q[4];
#pragma unroll
  for (int p = 0; p < 2; ++p) { int i4 = t + 256 * p; xn_cc[p] = i4 >> 4; xn_q[p] = (i4 & 15) * 4; }
#pragma unroll
  for (int p = 0; p < 4; ++p) { int i4 = t + 256 * p; xm_cc[p] = i4 >> 5; xm_q[p] = (i4 & 31) * 4; }

  int msbase = ms * (NDIM / MSPLIT);  // ms*512
  float4 pxn[2], pxm[4];
  auto issue = [&](int u) {  // u = mt*4+ch ; prefetch global->regs
    int m0u = msbase + (u >> 2) * 128;
    int c0u = (u & 3) * 32;
#pragma unroll
    for (int p = 0; p < 2; ++p)
      pxn[p] = *(const float4*)&xb[(size_t)(c0u + xn_cc[p]) * N + n0 + xn_q[p]];
#pragma unroll
    for (int p = 0; p < 4; ++p)
      pxm[p] = *(const float4*)&xb[(size_t)(c0u + xm_cc[p]) * N + m0u + xm_q[p]];
  };

  issue(0);
  const int NCHUNK = MT_PER * 4;  // 16

  for (int mt = 0; mt < MT_PER; ++mt) {
    int m0 = msbase + mt * 128;
    float acc[2][16];
#pragma unroll
    for (int i = 0; i < 2; ++i)
#pragma unroll
      for (int j = 0; j < 16; ++j) acc[i][j] = 0.f;

    for (int ch = 0; ch < 4; ++ch) {
      int u = mt * 4 + ch;
      __syncthreads();  // prior LDS consumers done
#pragma unroll
      for (int p = 0; p < 2; ++p) *(float4*)&xn[xn_cc[p] * 64 + xn_q[p]] = pxn[p];
#pragma unroll
      for (int p = 0; p < 4; ++p) *(float4*)&xm[xm_cc[p] * 128 + xm_q[p]] = pxm[p];
      if (ch == 0 && t < 128) xxs[t] = xxb[m0 + t];
      __syncthreads();
      if (u + 1 < NCHUNK) issue(u + 1);  // overlap next stage with compute

#pragma unroll 8
      for (int cc = 0; cc < 32; ++cc) {
        // a: 8 unique b64 addrs, broadcast over tx -> conflict-free
        float2 a = *(const float2*)&xn[cc * 64 + ty * 2];
        // b: 8 unique b128 addrs on distinct 4-bank groups -> conflict-free
        float4 b0 = *(const float4*)&xm[cc * 128 + tx * 4];
        float4 b1 = *(const float4*)&xm[cc * 128 + tx * 4 + 32];
        float4 b2 = *(const float4*)&xm[cc * 128 + tx * 4 + 64];
        float4 b3 = *(const float4*)&xm[cc * 128 + tx * 4 + 96];
        float bv[16] = {b0.x, b0.y, b0.z, b0.w, b1.x, b1.y, b1.z, b1.w,
                        b2.x, b2.y, b2.z, b2.w, b3.x, b3.y, b3.z, b3.w};
#pragma unroll
        for (int j = 0; j < 16; ++j) {
          acc[0][j] += a.x * bv[j];
          acc[1][j] += a.y * bv[j];
        }
      }
    }

    // score = 2*dot - ||x_m||^2 ; scan in registers (no LDS round trip)
    float xv[16];
#pragma unroll
    for (int jj = 0; jj < 4; ++jj) {
      float4 q4 = *(const float4*)&xxs[tx * 4 + jj * 32];
      xv[jj * 4 + 0] = q4.x; xv[jj * 4 + 1] = q4.y;
      xv[jj * 4 + 2] = q4.z; xv[jj * 4 + 3] = q4.w;
    }
#pragma unroll
    for (int i = 0; i < 2; ++i) {
#pragma unroll
      for (int j = 0; j < 16; ++j) {
        float v = 2.f * acc[i][j] - xv[j];
        int gm = m0 + tx * 4 + (j >> 2) * 32 + (j & 3);
        if (v > minv[i] || (v == minv[i] && gm < mini[i])) {
#pragma unroll
          for (int s = 0; s < KSEL; ++s)
            if (minp[i] == s) { tv[i][s] = v; ti[i][s] = gm; }
          minv[i] = tv[i][0]; mini[i] = ti[i][0]; minp[i] = 0;
#pragma unroll
          for (int s = 1; s < KSEL; ++s)
            if (tv[i][s] < minv[i] || (tv[i][s] == minv[i] && ti[i][s] > mini[i])) {
              minv[i] = tv[i][s]; mini[i] = ti[i][s]; minp[i] = s;
            }
        }
      }
    }
  }

  // sort each private list descending (val desc, idx asc) — static network
#pragma unroll
  for (int i = 0; i < 2; ++i)
#pragma unroll
    for (int a = 0; a < KSEL - 1; ++a)
#pragma unroll
      for (int b2 = 0; b2 < KSEL - 1 - a; ++b2)
        if (tv[i][b2] < tv[i][b2 + 1] ||
            (tv[i][b2] == tv[i][b2 + 1] && ti[i][b2] > ti[i][b2 + 1])) {
          float tf = tv[i][b2]; tv[i][b2] = tv[i][b2 + 1]; tv[i][b2 + 1] = tf;
          int tn = ti[i][b2]; ti[i][b2] = ti[i][b2 + 1]; ti[i][b2 + 1] = tn;
        }

  // merge 8 sorted per-thread lists per row -> sorted partial top-10, 2 halves
  float* mv = smem;                  // [32][80]
  int* mi = (int*)(smem + 2560);     // [32][80]
  for (int h = 0; h < 2; ++h) {
    __syncthreads();
    if ((ty >> 4) == h) {
      int rbase = 2 * ty - h * 32;
#pragma unroll
      for (int i = 0; i < 2; ++i)
#pragma unroll
        for (int s = 0; s < KSEL; ++s) {
          mv[(rbase + i) * 80 + tx * 10 + s] = tv[i][s];
          mi[(rbase + i) * 80 + tx * 10 + s] = ti[i][s];
        }
    }
    __syncthreads();
    if (t < 32) {
      int row = t;
      const float* rv = mv + row * 80;
      const int* ri = mi + row * 80;
      int hp[8];
#pragma unroll
      for (int q = 0; q < 8; ++q) hp[q] = 0;
      size_t obase = ((size_t)(bb * MSPLIT + ms) * N + n0 + h * 32 + row) * KSEL;
      for (int s = 0; s < KSEL; ++s) {
        float bv2 = -3e38f; int bi2 = 0x7fffffff; int bq = 0;
#pragma unroll
        for (int q = 0; q < 8; ++q) {
          if (hp[q] < KSEL) {
            float v = rv[q * 10 + hp[q]];
            int id = ri[q * 10 + hp[q]];
            if (v > bv2 || (v == bv2 && id < bi2)) { bv2 = v; bi2 = id; bq = q; }
          }
        }
#pragma unroll
        for (int q = 0; q < 8; ++q)
          if (bq == q) hp[q]++;
        pval[obase + s] = bv2;
        pidx[obase + s] = bi2;
      }
    }
  }
}

// ---------------------------------------------------------------------------
// Kernel B2: merge the 8 sorted split-partials per row -> final top-10 idx
// ---------------------------------------------------------------------------
__global__ __launch_bounds__(256) void merge_kernel(const float* __restrict__ pval,
                                                    const int* __restrict__ pidx,
                                                    int* __restrict__ idxout) {
  int g = blockIdx.x * 256 + threadIdx.x;  // 0..B*N-1
  int b = g >> 12;
  int n = g & (NDIM - 1);
  int hp[MSPLIT];
#pragma unroll
  for (int q = 0; q < MSPLIT; ++q) hp[q] = 0;
  int* op = idxout + ((size_t)b * NDIM + n) * KSEL;
  for (int s = 0; s < KSEL; ++s) {
    float bv = -3e38f; int bi = 0x7fffffff; int bq = 0;
#pragma unroll
    for (int q = 0; q < MSPLIT; ++q) {
      if (hp[q] < KSEL) {
        size_t o = ((size_t)(b * MSPLIT + q) * NDIM + n) * KSEL + hp[q];
        float v = pval[o];
        int id = pidx[o];
        if (v > bv || (v == bv && id < bi)) { bv = v; bi = id; bq = q; }
      }
    }
#pragma unroll
    for (int q = 0; q < MSPLIT; ++q)
      if (bq == q) hp[q]++;
    op[s] = bi;
  }
}

// ---------------------------------------------------------------------------
// Kernel C: Md[b][c][n] = mean_k x[b][c][idx[b][n][k]] - x[b][c][n]
// ---------------------------------------------------------------------------
__global__ __launch_bounds__(256) void gather_kernel(const float* __restrict__ x,
                                                     const int* __restrict__ idxg,
                                                     float* __restrict__ Md) {
  const int N = NDIM;
  int bb = blockIdx.y, c = blockIdx.x;
  __shared__ float row_s[NDIM];
  const float* rowg = x + (size_t)(bb * CDIM + c) * N;
  int t = threadIdx.x;
#pragma unroll
  for (int p = 0; p < 4; ++p) {
    int i4 = t + 256 * p;
    *(float4*)&row_s[i4 * 4] = *(const float4*)&rowg[i4 * 4];
  }
  __syncthreads();
  float* outp = Md + (size_t)(bb * CDIM + c) * N;
  const int* ib = idxg + (size_t)bb * N * KSEL;
  for (int p = 0; p < 16; ++p) {
    int n = t + 256 * p;
    const int* ip = ib + (size_t)n * KSEL;
    float s = 0.f;
#pragma unroll
    for (int k = 0; k < KSEL; ++k) s += row_s[ip[k]];
    outp[n] = s * 0.1f - row_s[n];
  }
}

// ---------------------------------------------------------------------------
// Kernel D: out[b][o][n] = sum_c W[o][c]*Md[b][c][n] + W[o][128+c]*x[b][c][n] + b[o]
// ---------------------------------------------------------------------------
__global__ __launch_bounds__(256) void out_kernel(const float* __restrict__ Md,
                                                  const float* __restrict__ x,
                                                  const float* __restrict__ W,
                                                  const float* __restrict__ bias,
                                                  float* __restrict__ out) {
  const int N = NDIM, O = 256;
  int bb = blockIdx.z;
  int o0 = blockIdx.y * 64;
  int n0 = blockIdx.x * 128;
  int t = threadIdx.x;
  int tx = t & 15, ty = t >> 4;
  int tx8 = tx * 8, ty4 = ty * 4;

  __shared__ float w1_s[32 * 64];    // [cc][o]
  __shared__ float w2_s[32 * 64];
  __shared__ float md_s[32 * 128];   // [cc][n]
  __shared__ float x_s[32 * 128];

  float acc[4][8];
#pragma unroll
  for (int i = 0; i < 4; ++i)
#pragma unroll
    for (int j = 0; j < 8; ++j) acc[i][j] = 0.f;

  for (int ch = 0; ch < 4; ++ch) {
    int c0 = ch * 32;
    __syncthreads();
#pragma unroll
    for (int p = 0; p < 2; ++p) {
      int i = t + 256 * p;  // 0..511
      int oo = i >> 3, q = i & 7;
      float4 v1 = *(const float4*)&W[(size_t)(o0 + oo) * 256 + c0 + q * 4];
      float4 v2 = *(const float4*)&W[(size_t)(o0 + oo) * 256 + 128 + c0 + q * 4];
      w1_s[(q * 4 + 0) * 64 + oo] = v1.x;
      w1_s[(q * 4 + 1) * 64 + oo] = v1.y;
      w1_s[(q * 4 + 2) * 64 + oo] = v1.z;
      w1_s[(q * 4 + 3) * 64 + oo] = v1.w;
      w2_s[(q * 4 + 0) * 64 + oo] = v2.x;
      w2_s[(q * 4 + 1) * 64 + oo] = v2.y;
      w2_s[(q * 4 + 2) * 64 + oo] = v2.z;
      w2_s[(q * 4 + 3) * 64 + oo] = v2.w;
    }
#pragma unroll
    for (int p = 0; p < 4; ++p) {
      int i = t + 256 * p;  // 0..1023
      int cc = i >> 5, q = (i & 31) * 4;
      *(float4*)&md_s[cc * 128 + q] =
          *(const float4*)&Md[(size_t)(bb * CDIM + c0 + cc) * N + n0 + q];
      *(float4*)&x_s[cc * 128 + q] =
          *(const float4*)&x[(size_t)(bb * CDIM + c0 + cc) * N + n0 + q];
    }
    __syncthreads();
#pragma unroll 8
    for (int cc = 0; cc < 32; ++cc) {
      float4 a1 = *(const float4*)&w1_s[cc * 64 + ty4];
      float4 a2 = *(const float4*)&w2_s[cc * 64 + ty4];
      float4 b1a = *(const float4*)&md_s[cc * 128 + tx8];
      float4 b1b = *(const float4*)&md_s[cc * 128 + tx8 + 4];
      float4 b2a = *(const float4*)&x_s[cc * 128 + tx8];
      float4 b2b = *(const float4*)&x_s[cc * 128 + tx8 + 4];
      float a1v[4] = {a1.x, a1.y, a1.z, a1.w};
      float a2v[4] = {a2.x, a2.y, a2.z, a2.w};
      float b1v[8] = {b1a.x, b1a.y, b1a.z, b1a.w, b1b.x, b1b.y, b1b.z, b1b.w};
      float b2v[8] = {b2a.x, b2a.y, b2a.z, b2a.w, b2b.x, b2b.y, b2b.z, b2b.w};
#pragma unroll
      for (int i = 0; i < 4; ++i)
#pragma unroll
        for (int j = 0; j < 8; ++j)
          acc[i][j] += a1v[i] * b1v[j] + a2v[i] * b2v[j];
    }
  }

#pragma unroll
  for (int i = 0; i < 4; ++i) {
    int o = o0 + ty4 + i;
    float bv = bias[o];
    float4 r0 = make_float4(acc[i][0] + bv, acc[i][1] + bv, acc[i][2] + bv, acc[i][3] + bv);
    float4 r1 = make_float4(acc[i][4] + bv, acc[i][5] + bv, acc[i][6] + bv, acc[i][7] + bv);
    float* po = out + (size_t)(bb * O + o) * N + n0 + tx8;
    *(float4*)&po[0] = r0;
    *(float4*)&po[4] = r1;
  }
}

// ---------------------------------------------------------------------------
extern "C" void kernel_launch(void* const* d_in, const int* in_sizes, int n_in,
                              void* d_out, int out_size, void* d_ws, size_t ws_size,
                              hipStream_t stream) {
  const float* x = (const float*)d_in[0];     // (4,128,4096) fp32
  const float* W = (const float*)d_in[1];     // (256,256,1,1) fp32
  const float* bias = (const float*)d_in[2];  // (256,) fp32
  float* out = (float*)d_out;                 // (4,256,4096) fp32

  // workspace carve (16B-aligned)
  float* xx = (float*)d_ws;                                      // 64 KB
  int* idx = (int*)((char*)d_ws + 65536);                        // 640 KB
  float* Md = (float*)((char*)d_ws + 65536 + 655360);            // 8 MB
  float* pval = (float*)((char*)d_ws + 9109504);                 // 5.25 MB
  int* pidx = (int*)((char*)d_ws + 9109504 + 5242880);           // 5.25 MB

  xx_kernel<<<dim3(256), 256, 0, stream>>>(x, xx);
  topk_kernel<<<dim3(64, MSPLIT, 4), 256, 0, stream>>>(x, xx, pval, pidx);
  merge_kernel<<<dim3(64), 256, 0, stream>>>(pval, pidx, idx);
  gather_kernel<<<dim3(128, 4), 256, 0, stream>>>(x, idx, Md);
  out_kernel<<<dim3(32, 4, 4), 256, 0, stream>>>(Md, x, W, bias, out);
}

// Round 3
// 615.528 us; speedup vs baseline: 1.5503x; 1.2581x over previous
//
#include <hip/hip_runtime.h>

#define BDIM 4
#define CDIM 128
#define NDIM 4096
#define KSEL 10
#define MSPLIT 8
#define MT_PER (NDIM / MSPLIT / 128)  // 4 m-tiles of 128 per block

// ---------------------------------------------------------------------------
// Kernel A: xx[b][n] = sum_c x[b][c][n]^2
// ---------------------------------------------------------------------------
__global__ __launch_bounds__(256) void xx_kernel(const float* __restrict__ x,
                                                 float* __restrict__ xx) {
  int t = threadIdx.x;
  int nl = t >> 2;
  int part = t & 3;
  int g = blockIdx.x * 64 + nl;      // 0..B*N-1
  int b = g >> 12;
  int n = g & (NDIM - 1);
  const float* xp = x + (size_t)b * CDIM * NDIM + n;
  float s = 0.f;
  int c0 = part * 32;
#pragma unroll
  for (int i = 0; i < 32; ++i) {
    float v = xp[(size_t)(c0 + i) * NDIM];
    s += v * v;
  }
  s += __shfl_xor(s, 1, 4);
  s += __shfl_xor(s, 2, 4);
  if (part == 0) xx[g] = s;
}

// ---------------------------------------------------------------------------
// Kernel B: fused distance-GEMM + top-10, m-split 8 ways.
// Block = 64 rows x 512 cols (4 m-tiles of 128). 256 threads.
// GEMM: thread tile 4 rows x 8 cols (acc=32 regs, 32 FMA : 3 ds_read_b128/c).
// Scores go to LDS (sc ALIASES the xn/xm staging space, 34KB total);
// scan: 4 threads/row, one private top-10 list per thread (20 regs, v1-proven
// register profile), bank-conflict-free layouts throughout.
// Emits per-(row,split) SORTED partial top-10 (val desc, idx asc).
// ---------------------------------------------------------------------------
__global__ __launch_bounds__(256, 4) void topk_kernel(const float* __restrict__ x,
                                                      const float* __restrict__ xxg,
                                                      float* __restrict__ pval,
                                                      int* __restrict__ pidx) {
  const int N = NDIM;
  int bb = blockIdx.z;
  int ms = blockIdx.y;
  int n0 = blockIdx.x * 64;
  int t = threadIdx.x;
  int tx = t & 15, ty = t >> 4;
  int tx4 = tx * 4, ty4 = ty * 4;

  __shared__ float smem[8448 + 128];
  float* xn = smem;            // [32][64]   2048 f  (aliased by sc)
  float* xm = smem + 2048;     // [32][128]  4096 f  (aliased by sc)
  float* sc = smem;            // [64][132]  8448 f  (aliases xn+xm)
  float* xxs = smem + 8448;    // [128]

  const float* xb = x + (size_t)bb * CDIM * N;
  const float* xxb = xxg + (size_t)bb * N;

  // one private top-10 list per thread (static indexing only)
  float tv[KSEL];
  int ti[KSEL];
#pragma unroll
  for (int s = 0; s < KSEL; ++s) { tv[s] = -1e30f; ti[s] = 0x7fffffff; }
  float minv = -1e30f;
  int mini = 0x7fffffff;
  int minp = 0;

  // staging address precompute (linear float4 layout -> conflict-free)
  int xn_cc[2], xn_q[2], xm_cc[4], xm_q[4];
#pragma unroll
  for (int p = 0; p < 2; ++p) { int i4 = t + 256 * p; xn_cc[p] = i4 >> 4; xn_q[p] = (i4 & 15) * 4; }
#pragma unroll
  for (int p = 0; p < 4; ++p) { int i4 = t + 256 * p; xm_cc[p] = i4 >> 5; xm_q[p] = (i4 & 31) * 4; }

  int msbase = ms * (NDIM / MSPLIT);  // ms*512
  float4 pxn[2], pxm[4];
  auto issue = [&](int u) {  // u = mt*4+ch ; prefetch global->regs
    int m0u = msbase + (u >> 2) * 128;
    int c0u = (u & 3) * 32;
#pragma unroll
    for (int p = 0; p < 2; ++p)
      pxn[p] = *(const float4*)&xb[(size_t)(c0u + xn_cc[p]) * N + n0 + xn_q[p]];
#pragma unroll
    for (int p = 0; p < 4; ++p)
      pxm[p] = *(const float4*)&xb[(size_t)(c0u + xm_cc[p]) * N + m0u + xm_q[p]];
  };

  issue(0);
  const int NCHUNK = MT_PER * 4;  // 16

  for (int mt = 0; mt < MT_PER; ++mt) {
    int m0 = msbase + mt * 128;
    float acc[4][8];
#pragma unroll
    for (int i = 0; i < 4; ++i)
#pragma unroll
      for (int j = 0; j < 8; ++j) acc[i][j] = 0.f;

    for (int ch = 0; ch < 4; ++ch) {
      int u = mt * 4 + ch;
      __syncthreads();  // prior LDS consumers (prev chunk GEMM / prev mt scan)
#pragma unroll
      for (int p = 0; p < 2; ++p) *(float4*)&xn[xn_cc[p] * 64 + xn_q[p]] = pxn[p];
#pragma unroll
      for (int p = 0; p < 4; ++p) *(float4*)&xm[xm_cc[p] * 128 + xm_q[p]] = pxm[p];
      if (ch == 0 && t < 128) xxs[t] = xxb[m0 + t];
      __syncthreads();
      if (u + 1 < NCHUNK) issue(u + 1);  // overlap next stage with compute

#pragma unroll 8
      for (int cc = 0; cc < 32; ++cc) {
        // a: 4 distinct b128 addrs on distinct banks, broadcast over tx
        float4 a = *(const float4*)&xn[cc * 64 + ty4];
        // b: 16 distinct b128 addrs, 2 per 4-bank group -> free
        float4 b0 = *(const float4*)&xm[cc * 128 + tx4];
        float4 b1 = *(const float4*)&xm[cc * 128 + tx4 + 64];
        float av[4] = {a.x, a.y, a.z, a.w};
        float bv[8] = {b0.x, b0.y, b0.z, b0.w, b1.x, b1.y, b1.z, b1.w};
#pragma unroll
        for (int i = 0; i < 4; ++i)
#pragma unroll
          for (int j = 0; j < 8; ++j) acc[i][j] += av[i] * bv[j];
      }
    }

    // all xn/xm reads done; write scores over the aliased region
    __syncthreads();
    {
      float4 xq0 = *(const float4*)&xxs[tx4];
      float4 xq1 = *(const float4*)&xxs[tx4 + 64];
      float xv[8] = {xq0.x, xq0.y, xq0.z, xq0.w, xq1.x, xq1.y, xq1.z, xq1.w};
#pragma unroll
      for (int i = 0; i < 4; ++i) {
        int r = ty4 + i;
        float4 s0 = make_float4(2.f * acc[i][0] - xv[0], 2.f * acc[i][1] - xv[1],
                                2.f * acc[i][2] - xv[2], 2.f * acc[i][3] - xv[3]);
        float4 s1 = make_float4(2.f * acc[i][4] - xv[4], 2.f * acc[i][5] - xv[5],
                                2.f * acc[i][6] - xv[6], 2.f * acc[i][7] - xv[7]);
        *(float4*)&sc[r * 132 + tx4] = s0;
        *(float4*)&sc[r * 132 + tx4 + 64] = s1;
      }
    }
    __syncthreads();

    // scan: thread (rr = t>>2, q = t&3) takes cols == q (mod 4)
    // bank = (4*rr + q + 4*i) mod 32 -> exactly 2 lanes/bank = free
    {
      int rr = t >> 2, q = t & 3;
      const float* srow = &sc[rr * 132 + q];
      int gbase = m0 + q;
#pragma unroll 8
      for (int i = 0; i < 32; ++i) {
        float v = srow[4 * i];
        int gm = gbase + 4 * i;
        if (v > minv || (v == minv && gm < mini)) {
#pragma unroll
          for (int s = 0; s < KSEL; ++s)
            if (minp == s) { tv[s] = v; ti[s] = gm; }
          minv = tv[0]; mini = ti[0]; minp = 0;
#pragma unroll
          for (int s = 1; s < KSEL; ++s)
            if (tv[s] < minv || (tv[s] == minv && ti[s] > mini)) {
              minv = tv[s]; mini = ti[s]; minp = s;
            }
        }
      }
    }
    // next mt's first-chunk barrier protects sc until staging overwrites it
  }

  // ----- merge 4 partial lists per row -> sorted partial top-10 -----
  __syncthreads();
  {
    int rr = t >> 2, q = t & 3;
    float* mv = smem;                   // [64][40]
    int* mi = (int*)(smem + 2560);      // [64][40]
#pragma unroll
    for (int s = 0; s < KSEL; ++s) {
      mv[rr * 40 + q * 10 + s] = tv[s];
      mi[rr * 40 + q * 10 + s] = ti[s];
    }
  }
  __syncthreads();
  if (t < 64) {
    int row = t;
    float* mv = smem + row * 40;
    int* mi = (int*)(smem + 2560) + row * 40;
    size_t obase = ((size_t)(bb * MSPLIT + ms) * N + n0 + row) * KSEL;
    for (int s = 0; s < KSEL; ++s) {
      float bvv = -3e38f;
      int bi = 0x7fffffff, bp = 0;
      for (int j = 0; j < 40; ++j) {
        float v = mv[j];
        int id = mi[j];
        if (v > bvv || (v == bvv && id < bi)) { bvv = v; bi = id; bp = j; }
      }
      mv[bp] = -3e38f;
      pval[obase + s] = bvv;
      pidx[obase + s] = bi;
    }
  }
}

// ---------------------------------------------------------------------------
// Kernel B2: merge the 8 sorted split-partials per row -> final top-10 idx
// ---------------------------------------------------------------------------
__global__ __launch_bounds__(256) void merge_kernel(const float* __restrict__ pval,
                                                    const int* __restrict__ pidx,
                                                    int* __restrict__ idxout) {
  int g = blockIdx.x * 256 + threadIdx.x;  // 0..B*N-1
  int b = g >> 12;
  int n = g & (NDIM - 1);
  int hp[MSPLIT];
#pragma unroll
  for (int q = 0; q < MSPLIT; ++q) hp[q] = 0;
  int* op = idxout + ((size_t)b * NDIM + n) * KSEL;
  for (int s = 0; s < KSEL; ++s) {
    float bv = -3e38f; int bi = 0x7fffffff; int bq = 0;
#pragma unroll
    for (int q = 0; q < MSPLIT; ++q) {
      if (hp[q] < KSEL) {
        size_t o = ((size_t)(b * MSPLIT + q) * NDIM + n) * KSEL + hp[q];
        float v = pval[o];
        int id = pidx[o];
        if (v > bv || (v == bv && id < bi)) { bv = v; bi = id; bq = q; }
      }
    }
#pragma unroll
    for (int q = 0; q < MSPLIT; ++q)
      if (bq == q) hp[q]++;
    op[s] = bi;
  }
}

// ---------------------------------------------------------------------------
// Kernel C: Md[b][c][n] = mean_k x[b][c][idx[b][n][k]] - x[b][c][n]
// ---------------------------------------------------------------------------
__global__ __launch_bounds__(256) void gather_kernel(const float* __restrict__ x,
                                                     const int* __restrict__ idxg,
                                                     float* __restrict__ Md) {
  const int N = NDIM;
  int bb = blockIdx.y, c = blockIdx.x;
  __shared__ float row_s[NDIM];
  const float* rowg = x + (size_t)(bb * CDIM + c) * N;
  int t = threadIdx.x;
#pragma unroll
  for (int p = 0; p < 4; ++p) {
    int i4 = t + 256 * p;
    *(float4*)&row_s[i4 * 4] = *(const float4*)&rowg[i4 * 4];
  }
  __syncthreads();
  float* outp = Md + (size_t)(bb * CDIM + c) * N;
  const int* ib = idxg + (size_t)bb * N * KSEL;
  for (int p = 0; p < 16; ++p) {
    int n = t + 256 * p;
    const int* ip = ib + (size_t)n * KSEL;
    float s = 0.f;
#pragma unroll
    for (int k = 0; k < KSEL; ++k) s += row_s[ip[k]];
    outp[n] = s * 0.1f - row_s[n];
  }
}

// ---------------------------------------------------------------------------
// Kernel D: out[b][o][n] = sum_c W[o][c]*Md[b][c][n] + W[o][128+c]*x[b][c][n] + b[o]
// ---------------------------------------------------------------------------
__global__ __launch_bounds__(256) void out_kernel(const float* __restrict__ Md,
                                                  const float* __restrict__ x,
                                                  const float* __restrict__ W,
                                                  const float* __restrict__ bias,
                                                  float* __restrict__ out) {
  const int N = NDIM, O = 256;
  int bb = blockIdx.z;
  int o0 = blockIdx.y * 64;
  int n0 = blockIdx.x * 128;
  int t = threadIdx.x;
  int tx = t & 15, ty = t >> 4;
  int tx8 = tx * 8, ty4 = ty * 4;

  __shared__ float w1_s[32 * 64];    // [cc][o]
  __shared__ float w2_s[32 * 64];
  __shared__ float md_s[32 * 128];   // [cc][n]
  __shared__ float x_s[32 * 128];

  float acc[4][8];
#pragma unroll
  for (int i = 0; i < 4; ++i)
#pragma unroll
    for (int j = 0; j < 8; ++j) acc[i][j] = 0.f;

  for (int ch = 0; ch < 4; ++ch) {
    int c0 = ch * 32;
    __syncthreads();
#pragma unroll
    for (int p = 0; p < 2; ++p) {
      int i = t + 256 * p;  // 0..511
      int oo = i >> 3, q = i & 7;
      float4 v1 = *(const float4*)&W[(size_t)(o0 + oo) * 256 + c0 + q * 4];
      float4 v2 = *(const float4*)&W[(size_t)(o0 + oo) * 256 + 128 + c0 + q * 4];
      w1_s[(q * 4 + 0) * 64 + oo] = v1.x;
      w1_s[(q * 4 + 1) * 64 + oo] = v1.y;
      w1_s[(q * 4 + 2) * 64 + oo] = v1.z;
      w1_s[(q * 4 + 3) * 64 + oo] = v1.w;
      w2_s[(q * 4 + 0) * 64 + oo] = v2.x;
      w2_s[(q * 4 + 1) * 64 + oo] = v2.y;
      w2_s[(q * 4 + 2) * 64 + oo] = v2.z;
      w2_s[(q * 4 + 3) * 64 + oo] = v2.w;
    }
#pragma unroll
    for (int p = 0; p < 4; ++p) {
      int i = t + 256 * p;  // 0..1023
      int cc = i >> 5, q = (i & 31) * 4;
      *(float4*)&md_s[cc * 128 + q] =
          *(const float4*)&Md[(size_t)(bb * CDIM + c0 + cc) * N + n0 + q];
      *(float4*)&x_s[cc * 128 + q] =
          *(const float4*)&x[(size_t)(bb * CDIM + c0 + cc) * N + n0 + q];
    }
    __syncthreads();
#pragma unroll 8
    for (int cc = 0; cc < 32; ++cc) {
      float4 a1 = *(const float4*)&w1_s[cc * 64 + ty4];
      float4 a2 = *(const float4*)&w2_s[cc * 64 + ty4];
      float4 b1a = *(const float4*)&md_s[cc * 128 + tx8];
      float4 b1b = *(const float4*)&md_s[cc * 128 + tx8 + 4];
      float4 b2a = *(const float4*)&x_s[cc * 128 + tx8];
      float4 b2b = *(const float4*)&x_s[cc * 128 + tx8 + 4];
      float a1v[4] = {a1.x, a1.y, a1.z, a1.w};
      float a2v[4] = {a2.x, a2.y, a2.z, a2.w};
      float b1v[8] = {b1a.x, b1a.y, b1a.z, b1a.w, b1b.x, b1b.y, b1b.z, b1b.w};
      float b2v[8] = {b2a.x, b2a.y, b2a.z, b2a.w, b2b.x, b2b.y, b2b.z, b2b.w};
#pragma unroll
      for (int i = 0; i < 4; ++i)
#pragma unroll
        for (int j = 0; j < 8; ++j)
          acc[i][j] += a1v[i] * b1v[j] + a2v[i] * b2v[j];
    }
  }

#pragma unroll
  for (int i = 0; i < 4; ++i) {
    int o = o0 + ty4 + i;
    float bv = bias[o];
    float4 r0 = make_float4(acc[i][0] + bv, acc[i][1] + bv, acc[i][2] + bv, acc[i][3] + bv);
    float4 r1 = make_float4(acc[i][4] + bv, acc[i][5] + bv, acc[i][6] + bv, acc[i][7] + bv);
    float* po = out + (size_t)(bb * O + o) * N + n0 + tx8;
    *(float4*)&po[0] = r0;
    *(float4*)&po[4] = r1;
  }
}

// ---------------------------------------------------------------------------
extern "C" void kernel_launch(void* const* d_in, const int* in_sizes, int n_in,
                              void* d_out, int out_size, void* d_ws, size_t ws_size,
                              hipStream_t stream) {
  const float* x = (const float*)d_in[0];     // (4,128,4096) fp32
  const float* W = (const float*)d_in[1];     // (256,256,1,1) fp32
  const float* bias = (const float*)d_in[2];  // (256,) fp32
  float* out = (float*)d_out;                 // (4,256,4096) fp32

  // workspace carve (16B-aligned)
  float* xx = (float*)d_ws;                                      // 64 KB
  int* idx = (int*)((char*)d_ws + 65536);                        // 640 KB
  float* Md = (float*)((char*)d_ws + 65536 + 655360);            // 8 MB
  float* pval = (float*)((char*)d_ws + 9109504);                 // 5.25 MB
  int* pidx = (int*)((char*)d_ws + 9109504 + 5242880);           // 5.25 MB

  xx_kernel<<<dim3(256), 256, 0, stream>>>(x, xx);
  topk_kernel<<<dim3(64, MSPLIT, 4), 256, 0, stream>>>(x, xx, pval, pidx);
  merge_kernel<<<dim3(64), 256, 0, stream>>>(pval, pidx, idx);
  gather_kernel<<<dim3(128, 4), 256, 0, stream>>>(x, idx, Md);
  out_kernel<<<dim3(32, 4, 4), 256, 0, stream>>>(Md, x, W, bias, out);
}